// Round 12
// baseline (3761.110 us; speedup 1.0000x reference)
//
#include <hip/hip_runtime.h>
#include <math.h>

#define BB    256
#define TT    2048
#define DZc   256
#define CLIPV 5.0f

__device__ __forceinline__ float softplus_f(float s) {
    return fmaxf(s, 0.0f) + log1pf(expf(-fabsf(s)));
}

__global__ __launch_bounds__(256)
__attribute__((amdgpu_waves_per_eu(1, 1)))
void plrnn_scan(const float* __restrict__ xin,   // (B,T,1)
                const float* __restrict__ z0,    // (B,DZ)
                const float* __restrict__ AW,    // (DZ,DZ)
                const float* __restrict__ h,     // (DZ)
                const float* __restrict__ Cw,    // (DZ,1)
                const float* __restrict__ Rw,    // (1,DZ)
                const float* __restrict__ Rb,    // (1)
                float* __restrict__ out)         // (B,T,1)
{
    __shared__ float part[2][4][DZc]; // 8KB double-buffered matvec partials
    __shared__ float xs[TT];          // 8KB input sequence
    __shared__ float ypr[512][4];     // 8KB y ring: [t mod 512][wave]
    __shared__ float ru[DZc][2];      // 2KB {relu(z), z*rw} per row, interleaved

    const int tid  = threadIdx.x;
    const int b    = blockIdx.x;
    const int l    = tid & 63;
    const int w    = tid >> 6;
    const int col0 = w * 64;          // this wave's column block == its own rows

    // ---- one-time: W[4l..4l+3][col0..col0+63] into 256 registers, diag=0 ----
    float wv[4][64];
    #pragma unroll
    for (int i = 0; i < 4; ++i) {
        const int row = 4 * l + i;
        const float* src = AW + row * DZc + col0;
        #pragma unroll
        for (int q = 0; q < 16; ++q) {
            float4 v = *reinterpret_cast<const float4*>(src + 4 * q);
            const int c = col0 + 4 * q;
            if (c + 0 == row) v.x = 0.0f;
            if (c + 1 == row) v.y = 0.0f;
            if (c + 2 == row) v.z = 0.0f;
            if (c + 3 == row) v.w = 0.0f;
            wv[i][4*q+0] = v.x; wv[i][4*q+1] = v.y;
            wv[i][4*q+2] = v.z; wv[i][4*q+3] = v.w;
        }
    }
    // opaque pin: forbid remat of the W registers inside the t-loop
    #pragma unroll
    for (int i = 0; i < 4; ++i)
        #pragma unroll
        for (int c = 0; c < 64; c += 4)
            asm volatile("" : "+v"(wv[i][c]), "+v"(wv[i][c+1]),
                              "+v"(wv[i][c+2]), "+v"(wv[i][c+3]));

    const float a_i  = AW[tid * DZc + tid];
    const float h_i  = h[tid];
    const float cw_i = Cw[tid];
    const float rw_i = Rw[tid];
    const float rb   = Rb[0];

    #pragma unroll
    for (int k = 0; k < TT / 256; ++k)
        xs[tid + 256 * k] = xin[b * TT + tid + 256 * k];

    float z = z0[b * DZc + tid];
    // stage {relu(z0), z0*rw}; phase 1 reads only this wave's own slice,
    // so same-wave LDS ordering (lgkmcnt) suffices -- barrier below is for xs.
    *reinterpret_cast<float2*>(&ru[tid][0]) =
        make_float2(fmaxf(z, 0.0f), z * rw_i);
    __syncthreads();

    // iteration t: state z=Z_t; computes Z_{t+1}; emits y_{t-1}=Z_t·Rw+rb
    for (int t = 0; t < TT; ++t) {
        // ---- phase 1: 64-col partial matvec + y partial ----
        // broadcast via uniform-address ds_read_b128 (LDS pipe, not VALU):
        // each b128 = {r[c],u[c],r[c+1],u[c+1]} for 2 columns of own slice.
        const float* rub = &ru[col0][0];
        float acc0 = 0.f, acc1 = 0.f, acc2 = 0.f, acc3 = 0.f, yac = 0.f;
        #pragma unroll
        for (int k = 0; k < 32; ++k) {
            const float4 q = *reinterpret_cast<const float4*>(rub + 4 * k);
            acc0 = fmaf(wv[0][2*k],   q.x, acc0);
            acc1 = fmaf(wv[1][2*k],   q.x, acc1);
            acc2 = fmaf(wv[2][2*k],   q.x, acc2);
            acc3 = fmaf(wv[3][2*k],   q.x, acc3);
            acc0 = fmaf(wv[0][2*k+1], q.z, acc0);
            acc1 = fmaf(wv[1][2*k+1], q.z, acc1);
            acc2 = fmaf(wv[2][2*k+1], q.z, acc2);
            acc3 = fmaf(wv[3][2*k+1], q.z, acc3);
            yac += q.y;
            yac += q.w;
        }
        if (l == 0 && t > 0) ypr[(t - 1) & 511][w] = yac;  // y_{t-1} partial

        *reinterpret_cast<float4*>(&part[t & 1][w][4 * l]) =
            make_float4(acc0, acc1, acc2, acc3);
        __syncthreads();                 // single barrier per step

        // ---- phase 2: combine partials, z-update, stage next {r,u} ----
        const float* pp = &part[t & 1][0][0];
        float s_ = pp[tid] + pp[DZc + tid] + pp[2*DZc + tid] + pp[3*DZc + tid];
        float zi = fmaf(a_i, z, s_);
        zi = fmaf(xs[t], cw_i, zi + h_i);
        zi = fminf(fmaxf(zi, -CLIPV), CLIPV);
        z = zi;
        *reinterpret_cast<float2*>(&ru[tid][0]) =
            make_float2(fmaxf(zi, 0.0f), zi * rw_i);

        // ---- amortized flush: 256 y's, coalesced, every 256 steps ----
        if ((t & 255) == 0 && t) {
            const int base = t - 256;
            const int slot = (base + tid) & 511;
            float4 yy = *reinterpret_cast<const float4*>(&ypr[slot][0]);
            out[(size_t)b * TT + base + tid] =
                softplus_f(yy.x + yy.y + yy.z + yy.w + rb);
        }
    }

    // ---- epilogue: y_{T-1} = Z_T · Rw from staged u, then flush last 256 ----
    {
        const float* rub = &ru[col0][0];
        float yac = 0.f;
        #pragma unroll
        for (int k = 0; k < 32; ++k) {
            const float4 q = *reinterpret_cast<const float4*>(rub + 4 * k);
            yac += q.y;
            yac += q.w;
        }
        if (l == 0) ypr[(TT - 1) & 511][w] = yac;
    }
    __syncthreads();
    {
        const int base = TT - 256;
        const int slot = (base + tid) & 511;
        float4 yy = *reinterpret_cast<const float4*>(&ypr[slot][0]);
        out[(size_t)b * TT + base + tid] =
            softplus_f(yy.x + yy.y + yy.z + yy.w + rb);
    }
}

extern "C" void kernel_launch(void* const* d_in, const int* in_sizes, int n_in,
                              void* d_out, int out_size, void* d_ws, size_t ws_size,
                              hipStream_t stream) {
    const float* xin = (const float*)d_in[0];
    const float* z0v = (const float*)d_in[1];
    const float* AW  = (const float*)d_in[2];
    const float* hv  = (const float*)d_in[3];
    const float* Cw  = (const float*)d_in[4];
    const float* Rw  = (const float*)d_in[5];
    const float* Rb  = (const float*)d_in[6];
    float* out = (float*)d_out;
    plrnn_scan<<<BB, 256, 0, stream>>>(xin, z0v, AW, hv, Cw, Rw, Rb, out);
}

// Round 13
// 1458.716 us; speedup vs baseline: 2.5784x; 2.5784x over previous
//
#include <hip/hip_runtime.h>
#include <math.h>

#define BB    256
#define TT    2048
#define DZc   256
#define CLIPV 5.0f

__device__ __forceinline__ float softplus_f(float s) {
    return fmaxf(s, 0.0f) + log1pf(expf(-fabsf(s)));
}

// uniform broadcast of lane `c`'s value via v_readlane (c in 0..31 here)
__device__ __forceinline__ float rl(float v, int c) {
    return __builtin_bit_cast(float,
        __builtin_amdgcn_readlane(__builtin_bit_cast(int, v), c));
}

// 8 waves (512 thr), 2 waves/SIMD pinned: 256-VGPR budget/wave, W tile
// (128 floats) fully register-resident; second wave hides latency.
__global__ __launch_bounds__(512)
__attribute__((amdgpu_waves_per_eu(2, 2)))
void plrnn_scan(const float* __restrict__ xin,   // (B,T,1)
                const float* __restrict__ z0,    // (B,DZ)
                const float* __restrict__ AW,    // (DZ,DZ)
                const float* __restrict__ h,     // (DZ)
                const float* __restrict__ Cw,    // (DZ,1)
                const float* __restrict__ Rw,    // (1,DZ)
                const float* __restrict__ Rb,    // (1)
                float* __restrict__ out)         // (B,T,1)
{
    __shared__ float part[2][8][DZc]; // 16KB double-buffered matvec partials
    __shared__ float xs[TT];          // 8KB input sequence
    __shared__ float ypr[512][8];     // 16KB y ring: [t mod 512][wave]

    const int tid  = threadIdx.x;
    const int b    = blockIdx.x;
    const int l    = tid & 63;
    const int w    = tid >> 6;        // wave 0..7
    const int col0 = w * 32;          // this wave's column block

    // ---- one-time: W[4l..4l+3][col0..col0+31] into 128 registers, diag=0 ----
    float wv[4][32];
    #pragma unroll
    for (int i = 0; i < 4; ++i) {
        const int row = 4 * l + i;
        const float* src = AW + row * DZc + col0;
        #pragma unroll
        for (int q = 0; q < 8; ++q) {
            float4 v = *reinterpret_cast<const float4*>(src + 4 * q);
            const int c = col0 + 4 * q;
            if (c + 0 == row) v.x = 0.0f;
            if (c + 1 == row) v.y = 0.0f;
            if (c + 2 == row) v.z = 0.0f;
            if (c + 3 == row) v.w = 0.0f;
            wv[i][4*q+0] = v.x; wv[i][4*q+1] = v.y;
            wv[i][4*q+2] = v.z; wv[i][4*q+3] = v.w;
        }
    }
    #pragma unroll
    for (int i = 0; i < 4; ++i)
        #pragma unroll
        for (int c = 0; c < 32; c += 4)
            asm volatile("" : "+v"(wv[i][c]), "+v"(wv[i][c+1]),
                              "+v"(wv[i][c+2]), "+v"(wv[i][c+3]));

    // ---- per-row state in lanes 0..31: row = col0 + (l&31) ----
    // (row block == col block, so the r-broadcast is same-wave readlane)
    const int myrow = col0 + (l & 31);
    float a_i = 0.f, h_i = 0.f, cw_i = 0.f, rw_i = 0.f, z = 0.f;
    if (l < 32) {
        a_i  = AW[myrow * DZc + myrow];
        h_i  = h[myrow];
        cw_i = Cw[myrow];
        rw_i = Rw[myrow];
        z    = z0[b * DZc + myrow];
    }
    const float rb = Rb[0];

    #pragma unroll
    for (int k = 0; k < TT / 512; ++k)
        xs[tid + 512 * k] = xin[b * TT + tid + 512 * k];

    float r = fmaxf(z, 0.f);          // relu(z), lanes 0..31
    float u = z * rw_i;               // z*Rw, lanes 0..31 (y contribution)
    __syncthreads();                  // xs ready

    // iteration t: state z=Z_t; computes Z_{t+1}; emits y_{t-1}
    for (int t = 0; t < TT; ++t) {
        // ---- y partial for t-1: 5-level butterfly over lanes 0..31 ----
        // issued first (DS pipe), consumed at end of phase 1 -> latency hidden
        float yac = u;
        yac += __shfl_xor(yac, 16, 32);
        yac += __shfl_xor(yac,  8, 32);
        yac += __shfl_xor(yac,  4, 32);
        yac += __shfl_xor(yac,  2, 32);
        yac += __shfl_xor(yac,  1, 32);

        // ---- phase 1: 32-col partial matvec via readlane broadcast ----
        float acc0 = 0.f, acc1 = 0.f, acc2 = 0.f, acc3 = 0.f;
        #pragma unroll
        for (int c = 0; c < 32; ++c) {
            const float rc = rl(r, c);   // relu(z)[col0+c] from lane c
            acc0 = fmaf(wv[0][c], rc, acc0);
            acc1 = fmaf(wv[1][c], rc, acc1);
            acc2 = fmaf(wv[2][c], rc, acc2);
            acc3 = fmaf(wv[3][c], rc, acc3);
        }
        if (l == 0 && t > 0) ypr[(t - 1) & 511][w] = yac;
        *reinterpret_cast<float4*>(&part[t & 1][w][4 * l]) =
            make_float4(acc0, acc1, acc2, acc3);
        __syncthreads();                 // single barrier per step

        // ---- phase 2: lanes 0..31 combine 8 partials, update row myrow ----
        if (l < 32) {
            const float* pp = &part[t & 1][0][myrow];
            float s_ = ((pp[0] + pp[DZc]) + (pp[2*DZc] + pp[3*DZc]))
                     + ((pp[4*DZc] + pp[5*DZc]) + (pp[6*DZc] + pp[7*DZc]));
            float zi = fmaf(a_i, z, s_);
            zi = fmaf(xs[t], cw_i, zi + h_i);
            zi = fminf(fmaxf(zi, -CLIPV), CLIPV);
            z = zi;
            r = fmaxf(zi, 0.f);
            u = zi * rw_i;
        }

        // ---- amortized flush: 256 y's, coalesced, every 256 steps ----
        if ((t & 255) == 0 && t && tid < 256) {
            const int base = t - 256;
            const int slot = (base + tid) & 511;
            const float* yy = &ypr[slot][0];
            float s8 = ((yy[0]+yy[1]) + (yy[2]+yy[3]))
                     + ((yy[4]+yy[5]) + (yy[6]+yy[7]));
            out[(size_t)b * TT + base + tid] = softplus_f(s8 + rb);
        }
    }

    // ---- epilogue: y_{T-1} from Z_T, then flush last 256 ----
    {
        float yac = u;
        yac += __shfl_xor(yac, 16, 32);
        yac += __shfl_xor(yac,  8, 32);
        yac += __shfl_xor(yac,  4, 32);
        yac += __shfl_xor(yac,  2, 32);
        yac += __shfl_xor(yac,  1, 32);
        if (l == 0) ypr[(TT - 1) & 511][w] = yac;
    }
    __syncthreads();
    if (tid < 256) {
        const int base = TT - 256;
        const int slot = (base + tid) & 511;
        const float* yy = &ypr[slot][0];
        float s8 = ((yy[0]+yy[1]) + (yy[2]+yy[3]))
                 + ((yy[4]+yy[5]) + (yy[6]+yy[7]));
        out[(size_t)b * TT + base + tid] = softplus_f(s8 + rb);
    }
}

extern "C" void kernel_launch(void* const* d_in, const int* in_sizes, int n_in,
                              void* d_out, int out_size, void* d_ws, size_t ws_size,
                              hipStream_t stream) {
    const float* xin = (const float*)d_in[0];
    const float* z0v = (const float*)d_in[1];
    const float* AW  = (const float*)d_in[2];
    const float* hv  = (const float*)d_in[3];
    const float* Cw  = (const float*)d_in[4];
    const float* Rw  = (const float*)d_in[5];
    const float* Rb  = (const float*)d_in[6];
    float* out = (float*)d_out;
    plrnn_scan<<<BB, 512, 0, stream>>>(xin, z0v, AW, hv, Cw, Rw, Rb, out);
}